// Round 1
// baseline (462.843 us; speedup 1.0000x reference)
//
#include <hip/hip_runtime.h>
#include <hip/hip_bf16.h>
#include <math.h>

#define N_IN 85680
#define PRE_K 5000
#define POST_K 750
#define NW 79            // ceil(PRE_K/64) words
#define NPAD 5056        // NW*64
#define STR 80           // mask row stride in u64 (79 used, 1 pad)
#define HSIZE 16384      // histogram buckets on score bits[31:18]
#define CAND_MAX 8192
#define CONF_THR 0.02f
#define NMS_THR 0.4f

typedef unsigned int u32;
typedef unsigned long long u64;

// opacity barrier: prevents FMA contraction so f32 math bit-matches numpy ref
__device__ __forceinline__ float opaquef(float x) { asm volatile("" : "+v"(x)); return x; }

// ---------------- histogram of valid score bits ----------------
__global__ __launch_bounds__(256) void hist_kernel(const float* __restrict__ conf,
                                                   u32* __restrict__ hist) {
    __shared__ u32 h[HSIZE];
    for (int b = threadIdx.x; b < HSIZE; b += 256) h[b] = 0u;
    __syncthreads();
    int i = blockIdx.x * 256 + threadIdx.x;
    if (i < N_IN) {
        float s = conf[2 * i + 1];
        if (s > CONF_THR) atomicAdd(&h[__float_as_uint(s) >> 18], 1u);
    }
    __syncthreads();
    for (int b = threadIdx.x; b < HSIZE; b += 256) {
        u32 v = h[b];
        if (v) atomicAdd(&hist[b], v);
    }
}

// ---------------- find bucket threshold B: max b with suffix(b) >= PRE_K ----------------
__global__ __launch_bounds__(1024) void scan_kernel(const u32* __restrict__ hist,
                                                    u32* __restrict__ bsel) {
    __shared__ u32 tot[1024];
    int c = threadIdx.x;
    u32 lh[16];
    u32 t = 0;
#pragma unroll
    for (int k = 0; k < 16; ++k) { lh[k] = hist[c * 16 + k]; t += lh[k]; }
    tot[c] = t;
    __syncthreads();
    for (int d = 1; d < 1024; d <<= 1) {
        u32 v = tot[c] + ((c + d < 1024) ? tot[c + d] : 0u);
        __syncthreads();
        tot[c] = v;
        __syncthreads();
    }
    u32 above = (c + 1 < 1024) ? tot[c + 1] : 0u;  // suffix starting at next chunk
    if (above < PRE_K && above + t >= PRE_K) {     // boundary chunk (unique)
        u32 cum = above;
        for (int k = 15; k >= 0; --k) {
            cum += lh[k];
            if (cum >= PRE_K) { bsel[0] = (u32)(c * 16 + k); break; }
        }
    }
    if (c == 0 && tot[0] < PRE_K) bsel[0] = 0u;   // fewer than PRE_K valid: take all
}

// ---------------- compact candidates (bucket >= B) as sortable keys ----------------
__global__ __launch_bounds__(256) void compact_kernel(const float* __restrict__ conf,
                                                      const u32* __restrict__ bsel,
                                                      u32* __restrict__ counter,
                                                      u64* __restrict__ cand) {
    int i = blockIdx.x * 256 + threadIdx.x;
    if (i >= N_IN) return;
    float sc = conf[2 * i + 1];
    if (sc <= CONF_THR) return;
    u32 bits = __float_as_uint(sc);
    if ((bits >> 18) < bsel[0]) return;
    u32 pos = atomicAdd(counter, 1u);
    // key: high = score bits (positive floats are order-isomorphic to uint),
    // low = ~i so larger key == (higher score, then lower index)  == lax.top_k order
    if (pos < CAND_MAX) cand[pos] = ((u64)bits << 32) | (u64)(u32)(~(u32)i);
}

// ---------------- one-block bitonic sort of 8192 keys, emit top PRE_K descending ----------------
__global__ __launch_bounds__(1024) void sort_kernel(const u64* __restrict__ cand,
                                                    const u32* __restrict__ counter,
                                                    u64* __restrict__ topk) {
    __shared__ u64 s[CAND_MAX];
    u32 cnt = *counter;
    if (cnt > CAND_MAX) cnt = CAND_MAX;
    for (int t = threadIdx.x; t < CAND_MAX; t += 1024) s[t] = (t < (int)cnt) ? cand[t] : 0ull;
    __syncthreads();
    for (int k = 2; k <= CAND_MAX; k <<= 1) {
        for (int j = k >> 1; j > 0; j >>= 1) {
            for (int p = threadIdx.x; p < CAND_MAX / 2; p += 1024) {
                int i = ((p & ~(j - 1)) << 1) | (p & (j - 1));
                int l = i | j;
                bool up = ((i & k) == 0);
                u64 a = s[i], b = s[l];
                if ((a > b) == up) { s[i] = b; s[l] = a; }
            }
            __syncthreads();
        }
    }
    // ascending in s; top r-th (descending) = s[CAND_MAX-1-r]
    for (int r = threadIdx.x; r < PRE_K; r += 1024) topk[r] = s[CAND_MAX - 1 - r];
}

// ---------------- decode boxes + landmarks for the selected 5000 ----------------
__global__ __launch_bounds__(256) void decode_kernel(const u64* __restrict__ topk,
                                                     const float4* __restrict__ loc4,
                                                     const float4* __restrict__ pri4,
                                                     const float* __restrict__ lmk,
                                                     const int* __restrict__ imw,
                                                     const int* __restrict__ imh,
                                                     float* __restrict__ rows,
                                                     float4* __restrict__ boxes,
                                                     u64* __restrict__ validm) {
    int r = blockIdx.x * 256 + threadIdx.x;
    if (r >= PRE_K) return;
    u64 key = topk[r];
    float* row = rows + (size_t)r * 16;
    if (key == 0ull) {
        boxes[r] = make_float4(-3e30f, -3e30f, -3e30f, -3e30f);  // zero-area, far away
#pragma unroll
        for (int c = 0; c < 16; ++c) row[c] = 0.f;
        return;
    }
    u32 i = ~(u32)key;
    float score = __uint_as_float((u32)(key >> 32));
    float4 L = loc4[i];
    float4 P = pri4[i];
    float W = (float)(*imw), H = (float)(*imh);
    float cx = P.x + opaquef((L.x * 0.1f) * P.z);
    float cy = P.y + opaquef((L.y * 0.1f) * P.w);
    // exp in f64 then round: ~correctly-rounded f32 exp (closest to numpy)
    float bw = P.z * (float)exp((double)(L.z * 0.2f));
    float bh = P.w * (float)exp((double)(L.w * 0.2f));
    float hw = opaquef(bw * 0.5f), hh = opaquef(bh * 0.5f);
    float x0 = (cx - hw) * W, y0 = (cy - hh) * H;
    float x1 = (cx + hw) * W, y1 = (cy + hh) * H;
    boxes[r] = make_float4(x0, y0, x1, y1);
    row[0] = x0; row[1] = y0; row[2] = x1; row[3] = y1; row[4] = score;
#pragma unroll
    for (int p = 0; p < 5; ++p) {
        float2 lm = ((const float2*)lmk)[(size_t)i * 5 + p];
        float lx = (P.x + opaquef((lm.x * 0.1f) * P.z)) * W;
        float ly = (P.y + opaquef((lm.y * 0.1f) * P.w)) * H;
        row[5 + 2 * p] = lx;
        row[6 + 2 * p] = ly;
    }
    row[15] = 0.f;
    atomicOr(&validm[r >> 6], 1ull << (r & 63));
}

// ---------------- pairwise IoU suppression bitmask (upper triangle only) ----------------
__global__ __launch_bounds__(64) void mask_kernel(const float4* __restrict__ boxes,
                                                  u64* __restrict__ mask) {
    int rc = blockIdx.x, cc = blockIdx.y;
    if (cc < rc) return;  // lower-triangle words left unwritten (never consulted)
    __shared__ float4 cb[64];
    int t = threadIdx.x;
    cb[t] = boxes[cc * 64 + t];
    int i = rc * 64 + t;
    float4 bi = boxes[i];
    __syncthreads();
    float areai = (bi.z - bi.x) * (bi.w - bi.y);
    u64 word = 0ull;
    int jbase = cc * 64;
#pragma unroll 4
    for (int k = 0; k < 64; ++k) {
        float4 bj = cb[k];
        float areaj = (bj.z - bj.x) * (bj.w - bj.y);
        float ltx = fmaxf(bi.x, bj.x), lty = fmaxf(bi.y, bj.y);
        float rbx = fminf(bi.z, bj.z), rby = fminf(bi.w, bj.w);
        float wx = fmaxf(rbx - ltx, 0.f), wy = fmaxf(rby - lty, 0.f);
        float inter = opaquef(wx * wy);
        float uni = fmaxf(areai + areaj - inter, 1e-12f);
        float iou = inter / uni;
        if ((jbase + k) > i && iou > NMS_THR) word |= (1ull << k);
    }
    mask[(size_t)i * STR + cc] = word;
}

// ---------------- single-wave greedy NMS reduce ----------------
__global__ __launch_bounds__(64) void reduce_kernel(const u64* __restrict__ mask,
                                                    const u64* __restrict__ validm,
                                                    u64* __restrict__ keepw,
                                                    u32* __restrict__ prefix) {
    int lane = threadIdx.x;
    u64 remv0 = 0ull, remv1 = 0ull, keep0 = 0ull, keep1 = 0ull;
    u64 valid0 = validm[lane];
    u64 valid1 = (lane < NW - 64) ? validm[64 + lane] : 0ull;
    for (int w = 0; w < NW; ++w) {
        u64 remw, valw;
        if (w < 64) {
            remw = __shfl(remv0, w);
            valw = __shfl(valid0, w);
        } else {
            remw = __shfl(remv1, w - 64);
            valw = __shfl(valid1, w - 64);
        }
        u64 cur = valw & ~remw;  // keep-candidates in this word
        while (cur) {
            int b = __ffsll(cur) - 1;
            int i = (w << 6) + b;  // kept box
            const u64* rowp = mask + (size_t)i * STR;
            u64 m0 = rowp[lane];
            u64 m1 = (lane < NW - 64) ? rowp[64 + lane] : 0ull;
            remv0 |= m0;
            remv1 |= m1;
            if (w < 64) {
                if (lane == w) keep0 |= (1ull << b);
            } else if (lane == w - 64) {
                keep1 |= (1ull << b);
            }
            u64 roww = (w < 64) ? __shfl(m0, w) : __shfl(m1, w - 64);
            cur &= ~(roww | (1ull << b));
        }
    }
    keepw[lane] = keep0;
    keepw[64 + lane] = keep1;
    __shared__ u32 pc[128];
    pc[lane] = (u32)__popcll(keep0);
    pc[64 + lane] = (u32)__popcll(keep1);
    __syncthreads();
    if (lane == 0) {
        u32 s = 0;
        for (int w = 0; w < NW; ++w) { prefix[w] = s; s += pc[w]; }
    }
}

// ---------------- scatter kept rows (rank < POST_K) ----------------
__global__ __launch_bounds__(256) void scatter_kernel(const float* __restrict__ rows,
                                                      const u64* __restrict__ keepw,
                                                      const u32* __restrict__ prefix,
                                                      float* __restrict__ out) {
    int r = blockIdx.x * 256 + threadIdx.x;
    if (r >= PRE_K) return;
    int w = r >> 6, b = r & 63;
    u64 kw = keepw[w];
    if (!((kw >> b) & 1ull)) return;
    u32 rank = prefix[w] + (u32)__popcll(kw & ((1ull << b) - 1ull));
    if (rank >= POST_K) return;
    const float* src = rows + (size_t)r * 16;
    float* dst = out + (size_t)rank * 15;
#pragma unroll
    for (int c = 0; c < 15; ++c) dst[c] = src[c];
}

extern "C" void kernel_launch(void* const* d_in, const int* in_sizes, int n_in,
                              void* d_out, int out_size, void* d_ws, size_t ws_size,
                              hipStream_t stream) {
    const float* loc = (const float*)d_in[0];
    const float* conf = (const float*)d_in[1];
    const float* lmk = (const float*)d_in[2];
    const float* pri = (const float*)d_in[3];
    const int* imw = (const int*)d_in[4];
    const int* imh = (const int*)d_in[5];
    float* out = (float*)d_out;
    char* base = (char*)d_ws;

    // workspace layout (bytes)
    u32* hist    = (u32*)(base + 0);        //  65536
    u32* counter = (u32*)(base + 65536);    //  64
    u32* bsel    = (u32*)(base + 65600);    //  64
    u64* validm  = (u64*)(base + 65664);    //  1024  (128 words)
    // zero region = [0, 66688)
    u64* keepw   = (u64*)(base + 66688);    //  1024  (128 words, fully written)
    u32* prefix  = (u32*)(base + 67712);    //  512
    u64* topk    = (u64*)(base + 68224);    //  40000
    u64* cand    = (u64*)(base + 108224);   //  65536
    float* rows  = (float*)(base + 173760); //  320000 (5000 x 16)
    float* boxes = (float*)(base + 493760); //  80896  (NPAD x 4)
    u64* mask    = (u64*)(base + 574656);   //  3235840 (NPAD x STR)  -> total ~3.64 MB

    hipMemsetAsync(d_ws, 0, 66688, stream);
    hipMemsetAsync(d_out, 0, (size_t)POST_K * 15 * sizeof(float), stream);

    hist_kernel<<<(N_IN + 255) / 256, 256, 0, stream>>>(conf, hist);
    scan_kernel<<<1, 1024, 0, stream>>>(hist, bsel);
    compact_kernel<<<(N_IN + 255) / 256, 256, 0, stream>>>(conf, bsel, counter, cand);
    sort_kernel<<<1, 1024, 0, stream>>>(cand, counter, topk);
    decode_kernel<<<(PRE_K + 255) / 256, 256, 0, stream>>>(topk, (const float4*)loc,
                                                           (const float4*)pri, lmk, imw, imh,
                                                           rows, (float4*)boxes, validm);
    mask_kernel<<<dim3(NW, NW), 64, 0, stream>>>((const float4*)boxes, mask);
    reduce_kernel<<<1, 64, 0, stream>>>(mask, validm, keepw, prefix);
    scatter_kernel<<<(PRE_K + 255) / 256, 256, 0, stream>>>(rows, keepw, prefix, out);
}